// Round 4
// baseline (1765.617 us; speedup 1.0000x reference)
//
#include <hip/hip_runtime.h>
#include <hip/hip_bf16.h>
#include <stdint.h>

// Problem constants (B=2, NV=25000, C=32, NR=3, ND=16, F=64)
#define NVERT 25000      // vertices per batch
#define NGRP5 10000      // groups of 5 vertices (50000/5, exact)

typedef __bf16  bf16x8 __attribute__((ext_vector_type(8)));
typedef float   f32x4  __attribute__((ext_vector_type(4)));

// ---- 16x16x32 design: f-quarter (n=16) B-pack, 49 K-chunks (48 conv + 1 center)
#define NKC     49
#define BPACK_Q_USHORT (NKC*512)        // ushorts per f-quarter pack (25088)
#define LDS_B16 (NKC*1024)              // 50176 B of B-fragments in LDS
#define SLOTV   1024                    // per-vert per-r patch: 16 rows x 64 B
#define WPATCH  (2*5*SLOTV)             // per-wave: 2 parity slots x 5 verts = 10240 B
#define LDS_TOT (LDS_B16 + 8*WPATCH)    // 132096 <= 163840; 1 block/CU, 2 waves/SIMD

__device__ __forceinline__ uint2 pack4(float4 v) {
  union { __hip_bfloat162 h; unsigned u; } a, b;
  a.h = __float22bfloat162_rn(float2{v.x, v.y});
  b.h = __float22bfloat162_rn(float2{v.z, v.w});
  return uint2{a.u, b.u};
}

__device__ __forceinline__ bf16x8 mkfrag(float4 a, float4 b) {
  union { bf16x8 v; uint2 u[2]; } t;
  t.u[0] = pack4(a);   // elems 0..3
  t.u[1] = pack4(b);   // elems 4..7
  return t.v;
}

__device__ __forceinline__ unsigned short f2bf(float f) {
  unsigned int u = __float_as_uint(f);
  u += 0x7FFFu + ((u >> 16) & 1u);   // round-to-nearest-even
  return (unsigned short)(u >> 16);
}

// lane-rotate within 16-lane rows (row_ror:15): dst[i] = src[(i+1)&15] — harness-verified.
// old = src (no invalid lanes for ror) -> compiler can emit a single in-place v_mov_b32_dpp.
__device__ __forceinline__ bf16x8 rot16(bf16x8 x) {
  union { bf16x8 v; int i[4]; } u;
  u.v = x;
#pragma unroll
  for (int k = 0; k < 4; ++k)
    u.i[k] = __builtin_amdgcn_update_dpp(u.i[k], u.i[k], 0x12F, 0xF, 0xF, false);
  return u.v;
}

// Pack kernel (3,16,32,64) + center_kernel (32,64) into 16x16x32 MFMA B-fragment order.
// Layout: bpack[fq(4)][kc(49)][lane(64)][i(8)] ushort.
// kc = r*16 + j for conv; kc = 48 for center. B[k][n]: n = lane&15, k = c = 8*(lane>>4)+i.
// (A staging uses the same c(lane,i) function, so the pairing is mapping-robust.)
__global__ __launch_bounds__(256) void prepack_kernel(
    const float* __restrict__ kern, const float* __restrict__ ckern,
    unsigned short* __restrict__ bpack)
{
  int tid = blockIdx.x*256 + threadIdx.x;
  if (tid >= 4*BPACK_Q_USHORT) return;
  int fq  = tid / BPACK_Q_USHORT;
  int rem = tid - fq*BPACK_Q_USHORT;
  int kc  = rem >> 9;
  int e   = rem & 511;
  int l   = e >> 3, i = e & 7;
  int f   = fq*16 + (l & 15);
  int c   = ((l >> 4) << 3) + i;
  float v;
  if (kc < 48) {
    int r = kc >> 4, j = kc & 15;
    v = kern[((r*16 + j)*32 + c)*64 + f];
  } else {
    v = ckern[c*64 + f];
  }
  bpack[tid] = f2bf(v);
}

// ---- staging macros (10 steps: step s covers vert v = s>>1, dir dd = (s&1)*8 + rsl) ----
#define EMLOAD(dst, gg, rr)                                                    \
  {                                                                            \
    const char* ebp = (const char*)em + (((size_t)(gg)*5)*48 + (rr)*16 + rsl)*8;\
    _Pragma("unroll")                                                          \
    for (int s = 0; s < 10; ++s)                                               \
      dst[s] = *(const int2*)(ebp + (s >> 1)*384 + (s & 1)*64);                \
  }

#define YISSUE(dst, eb)                                                        \
  {                                                                            \
    _Pragma("unroll")                                                          \
    for (int s = 0; s < 10; ++s) {                                             \
      const int rowi = eb[s].y + (eb[s].x ? NVERT : 0);                        \
      dst[s] = *(const float4*)((const char*)y + (size_t)rowi*128 + cp*16);    \
    }                                                                          \
  }

#define WRITE(parX, src)                                                       \
  {                                                                            \
    char* wp = swb + (parX)*5120;                                              \
    _Pragma("unroll")                                                          \
    for (int s = 0; s < 10; ++s)                                               \
      *(uint2*)(wp + (s >> 1)*1024 + (s & 1)*512) = pack4(src[s]);             \
  }

#define AREAD(parX)                                                            \
  {                                                                            \
    const char* ap = arb + (parX)*5120;                                        \
    a0 = *(const bf16x8*)(ap);                                                 \
    a1 = *(const bf16x8*)(ap + 1024);                                          \
    a2 = *(const bf16x8*)(ap + 2048);                                          \
    a3 = *(const bf16x8*)(ap + 3072);                                          \
    a4 = *(const bf16x8*)(ap + 4096);                                          \
  }

// One r-pass: B fragment per j (canonical lane*16 read, 0 conflicts), 5 MFMA per
// B-read (one per vertex), A rotated in-register over the direction dim (DPP).
#define JLOOP(rr)                                                              \
  {                                                                            \
    const char* bp = bbase + (size_t)(rr)*16384;                               \
    __builtin_amdgcn_s_setprio(1);                                             \
    _Pragma("unroll")                                                          \
    for (int j = 0; j < 16; ++j) {                                             \
      const bf16x8 b = *(const bf16x8*)(bp + (size_t)j*1024);                  \
      acc0 = __builtin_amdgcn_mfma_f32_16x16x32_bf16(a0, b, acc0, 0, 0, 0);    \
      acc1 = __builtin_amdgcn_mfma_f32_16x16x32_bf16(a1, b, acc1, 0, 0, 0);    \
      acc2 = __builtin_amdgcn_mfma_f32_16x16x32_bf16(a2, b, acc2, 0, 0, 0);    \
      acc3 = __builtin_amdgcn_mfma_f32_16x16x32_bf16(a3, b, acc3, 0, 0, 0);    \
      acc4 = __builtin_amdgcn_mfma_f32_16x16x32_bf16(a4, b, acc4, 0, 0, 0);    \
      if (j < 15) { a0 = rot16(a0); a1 = rot16(a1); a2 = rot16(a2);            \
                    a3 = rot16(a3); a4 = rot16(a4); }                          \
    }                                                                          \
    __builtin_amdgcn_s_setprio(0);                                             \
  }

__global__ __launch_bounds__(512, 2) void conv_kernel(
    const float* __restrict__ y,
    const int*   __restrict__ em,     // exp_map int pairs (b,v), flat (u*48 + r*16+dd)
    const float* __restrict__ bias,
    const unsigned short* __restrict__ bpack,
    float* __restrict__ out)
{
  extern __shared__ __align__(16) char smem[];
  const int fq  = blockIdx.x & 3;     // which 16-wide f quarter
  const int bl  = blockIdx.x >> 2;    // 0..63
  const int tid = threadIdx.x;
  const int w   = tid >> 6;           // wave 0..7
  const int l   = tid & 63;

  // ---- stage this f-quarter's B fragments into LDS (once per block) ----
  {
    const uint4* src = (const uint4*)(bpack + (size_t)fq * BPACK_Q_USHORT);
    uint4* dst = (uint4*)smem;
    for (int idx = tid; idx < LDS_B16/16; idx += 512) dst[idx] = src[idx];
  }
  __syncthreads();   // the ONLY barrier — B-pack is read-only afterwards

  const char* bbase = smem + (size_t)l * 16;     // canonical fragment read
  char* const patch = smem + LDS_B16 + w*WPATCH; // this wave's PRIVATE patch (2 slots x 5 verts)
  const int d  = l & 15;              // A-operand: direction row (m)
  const int g4 = l >> 4;              // A/B operand: k-group selector
  const float biasv = bias[fq*16 + d];

  // staging lane roles: 8 lanes x 16B cover a 128B fp32 row
  const int rsl = l >> 3, cp = l & 7;
  char* const swb = patch + rsl*64 + cp*8;       // + par*5120 + v*1024 + (s&1)*512
  const char* const arb = patch + d*64 + g4*16;  // + par*5120 + v*1024

  const int wid = bl*8 + w;           // wave-task id within this f-quarter: 0..511

  // ---- prologue: stage group wid's r=0 into slot0; em(r1) -> ebX ----
  int2 ebX[10], ebY[10];
  float4 yv[10];
  EMLOAD(ebY, wid, 0)
  YISSUE(yv, ebY)
  WRITE(0, yv)
  EMLOAD(ebX, wid, 1)

  int par = 0;
  for (int g = wid; g < NGRP5; g += 512) {
    const int gn = g + 512;
    const int gp = (gn < NGRP5) ? gn : g;   // clamped prefetch (results unused on last iter)

    f32x4 acc0, acc1, acc2, acc3, acc4;
#pragma unroll
    for (int k = 0; k < 4; ++k) { acc0[k]=0.f; acc1[k]=0.f; acc2[k]=0.f; acc3[k]=0.f; acc4[k]=0.f; }

    bf16x8 a0, a1, a2, a3, a4;

    // ---- phase 0: compute r=0 from slot par; stage r=1 -> slot par^1 ----
    AREAD(par)
    YISSUE(yv, ebX)        // y rows for r=1 (em prefetched last phase2/prologue)
    EMLOAD(ebY, g, 2)      // em for r=2
    JLOOP(0)
    WRITE(par^1, yv)

    // ---- phase 1: compute r=1 from slot par^1; stage r=2 -> slot par ----
    AREAD(par^1)
    YISSUE(yv, ebY)        // y rows for r=2
    EMLOAD(ebY, gp, 0)     // em for next iter r=0 (consume-then-reload)
    JLOOP(1)
    WRITE(par, yv)

    // ---- phase 2: compute r=2 from slot par; stage next r=0 -> slot par^1 ----
    AREAD(par)
    YISSUE(yv, ebY)        // y rows for next iter r=0
    EMLOAD(ebX, gp, 1)     // em for next iter r=1
    // center rows: direct global broadcast reads (vert g*5+v, fp32 c = g4*8..+7)
    float4 cy0[5], cy1[5];
#pragma unroll
    for (int v = 0; v < 5; ++v) {
      const char* cb = (const char*)y + (size_t)(g*5 + v)*128 + g4*32;
      cy0[v] = *(const float4*)(cb);
      cy1[v] = *(const float4*)(cb + 16);
    }
    JLOOP(2)
    WRITE(par^1, yv)

    // ---- center term: 5 MFMAs, A broadcast over d ----
    {
      const bf16x8 bc = *(const bf16x8*)(bbase + 48*1024);
      acc0 = __builtin_amdgcn_mfma_f32_16x16x32_bf16(mkfrag(cy0[0], cy1[0]), bc, acc0, 0, 0, 0);
      acc1 = __builtin_amdgcn_mfma_f32_16x16x32_bf16(mkfrag(cy0[1], cy1[1]), bc, acc1, 0, 0, 0);
      acc2 = __builtin_amdgcn_mfma_f32_16x16x32_bf16(mkfrag(cy0[2], cy1[2]), bc, acc2, 0, 0, 0);
      acc3 = __builtin_amdgcn_mfma_f32_16x16x32_bf16(mkfrag(cy0[3], cy1[3]), bc, acc3, 0, 0, 0);
      acc4 = __builtin_amdgcn_mfma_f32_16x16x32_bf16(mkfrag(cy0[4], cy1[4]), bc, acc4, 0, 0, 0);
    }

    // ---- epilogue: C/D 16x16 (m89): col = lane&15 = f, row = (lane>>4)*4+reg = dd.
    // max over dd = max over 4 regs then lane-groups (xor 16, 32); +bias, relu.
    {
      float m0 = fmaxf(fmaxf(acc0[0], acc0[1]), fmaxf(acc0[2], acc0[3]));
      float m1 = fmaxf(fmaxf(acc1[0], acc1[1]), fmaxf(acc1[2], acc1[3]));
      float m2 = fmaxf(fmaxf(acc2[0], acc2[1]), fmaxf(acc2[2], acc2[3]));
      float m3 = fmaxf(fmaxf(acc3[0], acc3[1]), fmaxf(acc3[2], acc3[3]));
      float m4 = fmaxf(fmaxf(acc4[0], acc4[1]), fmaxf(acc4[2], acc4[3]));
      m0 = fmaxf(m0, __shfl_xor(m0, 16)); m0 = fmaxf(m0, __shfl_xor(m0, 32));
      m1 = fmaxf(m1, __shfl_xor(m1, 16)); m1 = fmaxf(m1, __shfl_xor(m1, 32));
      m2 = fmaxf(m2, __shfl_xor(m2, 16)); m2 = fmaxf(m2, __shfl_xor(m2, 32));
      m3 = fmaxf(m3, __shfl_xor(m3, 16)); m3 = fmaxf(m3, __shfl_xor(m3, 32));
      m4 = fmaxf(m4, __shfl_xor(m4, 16)); m4 = fmaxf(m4, __shfl_xor(m4, 32));
      // verts g*5+0..3 via g4-select (all 64 lanes store distinct (vert, f))
      const float sel = (g4 == 0) ? m0 : (g4 == 1) ? m1 : (g4 == 2) ? m2 : m3;
      out[(size_t)(g*5 + g4)*64 + fq*16 + d] = fmaxf(sel + biasv, 0.f);
      // vert g*5+4: lanes 0..15
      if (l < 16)
        out[(size_t)(g*5 + 4)*64 + fq*16 + l] = fmaxf(m4 + biasv, 0.f);
    }

    par ^= 1;
  }
}

extern "C" void kernel_launch(void* const* d_in, const int* in_sizes, int n_in,
                              void* d_out, int out_size, void* d_ws, size_t ws_size,
                              hipStream_t stream) {
  const float* y     = (const float*)d_in[0];
  const int*   em    = (const int*)  d_in[1];
  const float* kern  = (const float*)d_in[2];
  const float* ckern = (const float*)d_in[3];
  const float* bias  = (const float*)d_in[4];
  float* out = (float*)d_out;
  unsigned short* bpack = (unsigned short*)d_ws;   // 200704 bytes used

  // opt in to >64KB dynamic LDS (host-side, graph-capture safe — verified many rounds)
  hipFuncSetAttribute(reinterpret_cast<const void*>(conv_kernel),
                      hipFuncAttributeMaxDynamicSharedMemorySize, LDS_TOT);

  prepack_kernel<<<(4*BPACK_Q_USHORT + 255)/256, 256, 0, stream>>>(kern, ckern, bpack);
  conv_kernel<<<256, 512, LDS_TOT, stream>>>(y, em, bias, bpack, out);
}

// Round 5
// 1201.818 us; speedup vs baseline: 1.4691x; 1.4691x over previous
//
#include <hip/hip_runtime.h>
#include <hip/hip_bf16.h>
#include <stdint.h>

// Problem constants (B=2, NV=25000, C=32, NR=3, ND=16, F=64)
#define NVERT 25000      // vertices per batch
#define NGRP5 10000      // groups of 5 vertices (50000/5, exact)

typedef __bf16  bf16x8 __attribute__((ext_vector_type(8)));
typedef float   f32x4  __attribute__((ext_vector_type(4)));

// ---- 16x16x32 design: f-quarter (n=16) B-pack, 49 K-chunks (48 conv + 1 center)
#define NKC     49
#define BPACK_Q_USHORT (NKC*512)        // ushorts per f-quarter pack (25088)
#define LDS_B16 (NKC*1024)              // 50176 B of B-fragments in LDS
#define SLOTV   1024                    // per-vert per-r patch: 16 rows x 64 B
#define WPATCH  (2*5*SLOTV + 320)       // 2 parity slots x 5 verts + center rows = 10560 B
#define LDS_TOT (LDS_B16 + 8*WPATCH)    // 134656 <= 163840; 1 block/CU, 2 waves/SIMD

__device__ __forceinline__ uint2 pack4(float4 v) {
  union { __hip_bfloat162 h; unsigned u; } a, b;
  a.h = __float22bfloat162_rn(float2{v.x, v.y});
  b.h = __float22bfloat162_rn(float2{v.z, v.w});
  return uint2{a.u, b.u};
}

__device__ __forceinline__ unsigned short f2bf(float f) {
  unsigned int u = __float_as_uint(f);
  u += 0x7FFFu + ((u >> 16) & 1u);   // round-to-nearest-even
  return (unsigned short)(u >> 16);
}

// lane-rotate within 16-lane rows (row_ror:15): dst[i] = src[(i+1)&15] — harness-verified
// in-place form (R3 passed): single v_mov_b32_dpp per dword.
__device__ __forceinline__ bf16x8 rot16(bf16x8 x) {
  union { bf16x8 v; int i[4]; } u;
  u.v = x;
#pragma unroll
  for (int k = 0; k < 4; ++k)
    u.i[k] = __builtin_amdgcn_update_dpp(u.i[k], u.i[k], 0x12F, 0xF, 0xF, false);
  return u.v;
}

// Pack kernel (3,16,32,64) + center_kernel (32,64) into 16x16x32 MFMA B-fragment order.
// Layout: bpack[fq(4)][kc(49)][lane(64)][i(8)] ushort.
// kc = r*16 + j for conv; kc = 48 for center. B[k][n]: n = lane&15, k = c = 8*(lane>>4)+i.
__global__ __launch_bounds__(256) void prepack_kernel(
    const float* __restrict__ kern, const float* __restrict__ ckern,
    unsigned short* __restrict__ bpack)
{
  int tid = blockIdx.x*256 + threadIdx.x;
  if (tid >= 4*BPACK_Q_USHORT) return;
  int fq  = tid / BPACK_Q_USHORT;
  int rem = tid - fq*BPACK_Q_USHORT;
  int kc  = rem >> 9;
  int e   = rem & 511;
  int l   = e >> 3, i = e & 7;
  int f   = fq*16 + (l & 15);
  int c   = ((l >> 4) << 3) + i;
  float v;
  if (kc < 48) {
    int r = kc >> 4, j = kc & 15;
    v = kern[((r*16 + j)*32 + c)*64 + f];
  } else {
    v = ckern[c*64 + f];
  }
  bpack[tid] = f2bf(v);
}

// ---- staging macros (10 steps: step s covers vert v = s>>1, dir dd = (s&1)*8 + rsl) ----
// em -> row index immediately (10 regs, not 20)
#define EMLOAD(dst, gg, rr)                                                    \
  {                                                                            \
    const char* ebp = (const char*)em + (((size_t)(gg)*5)*48 + (rr)*16 + rsl)*8;\
    _Pragma("unroll")                                                          \
    for (int s = 0; s < 10; ++s) {                                             \
      const int2 e = *(const int2*)(ebp + (s >> 1)*384 + (s & 1)*64);          \
      dst[s] = e.y + (e.x ? NVERT : 0);                                        \
    }                                                                          \
  }

// y rows: load float4 + pack to uint2 ON ARRIVAL (20 regs live, not 40)
#define YSTAGE(dst, rb)                                                        \
  {                                                                            \
    _Pragma("unroll")                                                          \
    for (int s = 0; s < 10; ++s)                                               \
      dst[s] = pack4(*(const float4*)((const char*)y + (size_t)rb[s]*128 + cp*16));\
  }

#define WRITE(parX, src)                                                       \
  {                                                                            \
    char* wp = swb + (parX)*5120;                                              \
    _Pragma("unroll")                                                          \
    for (int s = 0; s < 10; ++s)                                               \
      *(uint2*)(wp + (s >> 1)*1024 + (s & 1)*512) = src[s];                    \
  }

#define AREAD(parX)                                                            \
  {                                                                            \
    const char* ap = arb + (parX)*5120;                                        \
    a0 = *(const bf16x8*)(ap);                                                 \
    a1 = *(const bf16x8*)(ap + 1024);                                          \
    a2 = *(const bf16x8*)(ap + 2048);                                          \
    a3 = *(const bf16x8*)(ap + 3072);                                          \
    a4 = *(const bf16x8*)(ap + 4096);                                          \
  }

// One r-pass: B fragment per j (canonical lane*16 read, 0 conflicts), 5 MFMA per
// B-read (one per vertex), A rotated in-register over the direction dim (DPP).
#define JLOOP(rr)                                                              \
  {                                                                            \
    const char* bp = bbase + (size_t)(rr)*16384;                               \
    __builtin_amdgcn_s_setprio(1);                                             \
    _Pragma("unroll")                                                          \
    for (int j = 0; j < 16; ++j) {                                             \
      const bf16x8 b = *(const bf16x8*)(bp + (size_t)j*1024);                  \
      acc0 = __builtin_amdgcn_mfma_f32_16x16x32_bf16(a0, b, acc0, 0, 0, 0);    \
      acc1 = __builtin_amdgcn_mfma_f32_16x16x32_bf16(a1, b, acc1, 0, 0, 0);    \
      acc2 = __builtin_amdgcn_mfma_f32_16x16x32_bf16(a2, b, acc2, 0, 0, 0);    \
      acc3 = __builtin_amdgcn_mfma_f32_16x16x32_bf16(a3, b, acc3, 0, 0, 0);    \
      acc4 = __builtin_amdgcn_mfma_f32_16x16x32_bf16(a4, b, acc4, 0, 0, 0);    \
      if (j < 15) { a0 = rot16(a0); a1 = rot16(a1); a2 = rot16(a2);            \
                    a3 = rot16(a3); a4 = rot16(a4); }                          \
    }                                                                          \
    __builtin_amdgcn_s_setprio(0);                                             \
  }

__global__ __launch_bounds__(512, 2) void conv_kernel(
    const float* __restrict__ y,
    const int*   __restrict__ em,     // exp_map int pairs (b,v), flat (u*48 + r*16+dd)
    const float* __restrict__ bias,
    const unsigned short* __restrict__ bpack,
    float* __restrict__ out)
{
  extern __shared__ __align__(16) char smem[];
  const int fq  = blockIdx.x & 3;     // which 16-wide f quarter
  const int bl  = blockIdx.x >> 2;    // 0..63
  const int tid = threadIdx.x;
  const int w   = tid >> 6;           // wave 0..7
  const int l   = tid & 63;

  // ---- stage this f-quarter's B fragments into LDS (once per block) ----
  {
    const uint4* src = (const uint4*)(bpack + (size_t)fq * BPACK_Q_USHORT);
    uint4* dst = (uint4*)smem;
    for (int idx = tid; idx < LDS_B16/16; idx += 512) dst[idx] = src[idx];
  }
  __syncthreads();   // the ONLY barrier — B-pack is read-only afterwards

  const char* bbase = smem + (size_t)l * 16;     // canonical fragment read
  char* const patch = smem + LDS_B16 + w*WPATCH; // PRIVATE: 2 slots x 5 verts + center
  const int d  = l & 15;              // A-operand: direction row (m)
  const int g4 = l >> 4;              // A/B operand: k-group selector
  const float biasv = bias[fq*16 + d];

  // staging lane roles: 8 lanes x 16B cover a 128B fp32 row
  const int rsl = l >> 3, cp = l & 7;
  char* const swb = patch + rsl*64 + cp*8;       // + par*5120 + v*1024 + (s&1)*512
  const char* const arb = patch + d*64 + g4*16;  // + par*5120 + v*1024
  char* const cwb = patch + 2*5120 + rsl*64 + cp*8;   // center write (lanes 0..39)
  const char* const crb = patch + 2*5120 + g4*16;     // center read (+v*64, bcast over d)

  const int wid = bl*8 + w;           // wave-task id within this f-quarter: 0..511

  int rowiX[10], rowiY[10];
  uint2 sv[10];

  // ---- prologue: stage group wid's r=0 into slot0; em(r1) -> rowiX ----
  EMLOAD(rowiY, wid, 0)
  YSTAGE(sv, rowiY)
  WRITE(0, sv)
  EMLOAD(rowiX, wid, 1)

  int par = 0;
  for (int g = wid; g < NGRP5; g += 512) {
    const int gn = g + 512;
    const int gp = (gn < NGRP5) ? gn : g;   // clamped prefetch (results unused on last iter)

    f32x4 acc0, acc1, acc2, acc3, acc4;
#pragma unroll
    for (int k = 0; k < 4; ++k) { acc0[k]=0.f; acc1[k]=0.f; acc2[k]=0.f; acc3[k]=0.f; acc4[k]=0.f; }

    bf16x8 a0, a1, a2, a3, a4;

    // ---- phase 0: compute r=0 from slot par; stage r=1 -> slot par^1 ----
    AREAD(par)
    YSTAGE(sv, rowiX)      // r=1 rows (em prefetched last phase 2 / prologue)
    // center rows for g -> LDS (lanes 0..39; 5 rows x 64B bf16), read after JLOOP(0)
    if (l < 40)
      *(uint2*)(cwb) = pack4(*(const float4*)((const char*)y + (size_t)(g*5 + rsl)*128 + cp*16));
    EMLOAD(rowiY, g, 2)    // em for r=2
    JLOOP(0)
    WRITE(par^1, sv)

    // ---- center term: A broadcast over d from LDS (transient frags, 5 MFMAs) ----
    {
      const bf16x8 bc = *(const bf16x8*)(bbase + 48*1024);
      acc0 = __builtin_amdgcn_mfma_f32_16x16x32_bf16(*(const bf16x8*)(crb),        bc, acc0, 0, 0, 0);
      acc1 = __builtin_amdgcn_mfma_f32_16x16x32_bf16(*(const bf16x8*)(crb + 64),   bc, acc1, 0, 0, 0);
      acc2 = __builtin_amdgcn_mfma_f32_16x16x32_bf16(*(const bf16x8*)(crb + 128),  bc, acc2, 0, 0, 0);
      acc3 = __builtin_amdgcn_mfma_f32_16x16x32_bf16(*(const bf16x8*)(crb + 192),  bc, acc3, 0, 0, 0);
      acc4 = __builtin_amdgcn_mfma_f32_16x16x32_bf16(*(const bf16x8*)(crb + 256),  bc, acc4, 0, 0, 0);
    }

    // ---- phase 1: compute r=1 from slot par^1; stage r=2 -> slot par ----
    AREAD(par^1)
    YSTAGE(sv, rowiY)      // r=2 rows
    EMLOAD(rowiY, gp, 0)   // em for next iter r=0 (consume-then-reload)
    JLOOP(1)
    WRITE(par, sv)

    // ---- phase 2: compute r=2 from slot par; stage next r=0 -> slot par^1 ----
    AREAD(par)
    YSTAGE(sv, rowiY)      // next iter r=0 rows
    EMLOAD(rowiX, gp, 1)   // em for next iter r=1
    JLOOP(2)
    WRITE(par^1, sv)

    // ---- epilogue: C/D 16x16 (m89): col = lane&15 = f, row = (lane>>4)*4+reg = dd.
    // max over dd = max over 4 regs then lane-groups (xor 16, 32); +bias, relu.
    {
      float m0 = fmaxf(fmaxf(acc0[0], acc0[1]), fmaxf(acc0[2], acc0[3]));
      float m1 = fmaxf(fmaxf(acc1[0], acc1[1]), fmaxf(acc1[2], acc1[3]));
      float m2 = fmaxf(fmaxf(acc2[0], acc2[1]), fmaxf(acc2[2], acc2[3]));
      float m3 = fmaxf(fmaxf(acc3[0], acc3[1]), fmaxf(acc3[2], acc3[3]));
      float m4 = fmaxf(fmaxf(acc4[0], acc4[1]), fmaxf(acc4[2], acc4[3]));
      m0 = fmaxf(m0, __shfl_xor(m0, 16)); m0 = fmaxf(m0, __shfl_xor(m0, 32));
      m1 = fmaxf(m1, __shfl_xor(m1, 16)); m1 = fmaxf(m1, __shfl_xor(m1, 32));
      m2 = fmaxf(m2, __shfl_xor(m2, 16)); m2 = fmaxf(m2, __shfl_xor(m2, 32));
      m3 = fmaxf(m3, __shfl_xor(m3, 16)); m3 = fmaxf(m3, __shfl_xor(m3, 32));
      m4 = fmaxf(m4, __shfl_xor(m4, 16)); m4 = fmaxf(m4, __shfl_xor(m4, 32));
      // verts g*5+0..3 via g4-select (all 64 lanes store distinct (vert, f))
      const float sel = (g4 == 0) ? m0 : (g4 == 1) ? m1 : (g4 == 2) ? m2 : m3;
      out[(size_t)(g*5 + g4)*64 + fq*16 + d] = fmaxf(sel + biasv, 0.f);
      // vert g*5+4: lanes 0..15
      if (l < 16)
        out[(size_t)(g*5 + 4)*64 + fq*16 + l] = fmaxf(m4 + biasv, 0.f);
    }

    par ^= 1;
  }
}

extern "C" void kernel_launch(void* const* d_in, const int* in_sizes, int n_in,
                              void* d_out, int out_size, void* d_ws, size_t ws_size,
                              hipStream_t stream) {
  const float* y     = (const float*)d_in[0];
  const int*   em    = (const int*)  d_in[1];
  const float* kern  = (const float*)d_in[2];
  const float* ckern = (const float*)d_in[3];
  const float* bias  = (const float*)d_in[4];
  float* out = (float*)d_out;
  unsigned short* bpack = (unsigned short*)d_ws;   // 200704 bytes used

  // opt in to >64KB dynamic LDS (host-side, graph-capture safe — verified many rounds)
  hipFuncSetAttribute(reinterpret_cast<const void*>(conv_kernel),
                      hipFuncAttributeMaxDynamicSharedMemorySize, LDS_TOT);

  prepack_kernel<<<(4*BPACK_Q_USHORT + 255)/256, 256, 0, stream>>>(kern, ckern, bpack);
  conv_kernel<<<256, 512, LDS_TOT, stream>>>(y, em, bias, bpack, out);
}

// Round 6
// 1195.145 us; speedup vs baseline: 1.4773x; 1.0056x over previous
//
#include <hip/hip_runtime.h>
#include <hip/hip_bf16.h>
#include <stdint.h>

// Problem constants (B=2, NV=25000, C=32, NR=3, ND=16, F=64)
#define NVERT 25000      // vertices per batch
#define NGRP5 10000      // groups of 5 vertices (50000/5, exact)

typedef __bf16  bf16x8 __attribute__((ext_vector_type(8)));
typedef float   f32x4  __attribute__((ext_vector_type(4)));

// ---- 16x16x32 design: f-quarter (n=16) B-pack, 49 K-chunks (48 conv + 1 center)
#define NKC     49
#define BPACK_Q_USHORT (NKC*512)        // ushorts per f-quarter pack (25088)
#define LDS_B16 (NKC*1024)              // 50176 B of B-fragments in LDS
#define SLOTV   1024                    // per-vert per-r patch: 16 rows x 64 B
#define WPATCH  (2*5*SLOTV + 320)       // 2 parity slots x 5 verts + center rows = 10560 B
#define LDS_TOT (LDS_B16 + 8*WPATCH)    // 134656 <= 163840; 1 block/CU (LDS-bound), 2 waves/SIMD

__device__ __forceinline__ uint2 pack4(float4 v) {
  union { __hip_bfloat162 h; unsigned u; } a, b;
  a.h = __float22bfloat162_rn(float2{v.x, v.y});
  b.h = __float22bfloat162_rn(float2{v.z, v.w});
  return uint2{a.u, b.u};
}

__device__ __forceinline__ unsigned short f2bf(float f) {
  unsigned int u = __float_as_uint(f);
  u += 0x7FFFu + ((u >> 16) & 1u);   // round-to-nearest-even
  return (unsigned short)(u >> 16);
}

// lane-rotate within 16-lane rows (row_ror:15): dst[i] = src[(i+1)&15] — harness-verified
// in-place form (R3/R5 passed): single v_mov_b32_dpp per dword.
__device__ __forceinline__ bf16x8 rot16(bf16x8 x) {
  union { bf16x8 v; int i[4]; } u;
  u.v = x;
#pragma unroll
  for (int k = 0; k < 4; ++k)
    u.i[k] = __builtin_amdgcn_update_dpp(u.i[k], u.i[k], 0x12F, 0xF, 0xF, false);
  return u.v;
}

// Pack kernel (3,16,32,64) + center_kernel (32,64) into 16x16x32 MFMA B-fragment order.
// Layout: bpack[fq(4)][kc(49)][lane(64)][i(8)] ushort.
// kc = r*16 + j for conv; kc = 48 for center. B[k][n]: n = lane&15, k = c = 8*(lane>>4)+i.
__global__ __launch_bounds__(256) void prepack_kernel(
    const float* __restrict__ kern, const float* __restrict__ ckern,
    unsigned short* __restrict__ bpack)
{
  int tid = blockIdx.x*256 + threadIdx.x;
  if (tid >= 4*BPACK_Q_USHORT) return;
  int fq  = tid / BPACK_Q_USHORT;
  int rem = tid - fq*BPACK_Q_USHORT;
  int kc  = rem >> 9;
  int e   = rem & 511;
  int l   = e >> 3, i = e & 7;
  int f   = fq*16 + (l & 15);
  int c   = ((l >> 4) << 3) + i;
  float v;
  if (kc < 48) {
    int r = kc >> 4, j = kc & 15;
    v = kern[((r*16 + j)*32 + c)*64 + f];
  } else {
    v = ckern[c*64 + f];
  }
  bpack[tid] = f2bf(v);
}

// ---- staging macros (10 steps: step s covers vert v = s>>1, dir dd = (s&1)*8 + rsl) ----
// em -> row index immediately (10 regs, not 20)
#define EMLOAD(dst, gg, rr)                                                    \
  {                                                                            \
    const char* ebp = (const char*)em + (((size_t)(gg)*5)*48 + (rr)*16 + rsl)*8;\
    _Pragma("unroll")                                                          \
    for (int s = 0; s < 10; ++s) {                                             \
      const int2 e = *(const int2*)(ebp + (s >> 1)*384 + (s & 1)*64);          \
      dst[s] = e.y + (e.x ? NVERT : 0);                                        \
    }                                                                          \
  }

// y rows: load float4 + pack to uint2 ON ARRIVAL (20 regs live, not 40)
#define YSTAGE(dst, rb)                                                        \
  {                                                                            \
    _Pragma("unroll")                                                          \
    for (int s = 0; s < 10; ++s)                                               \
      dst[s] = pack4(*(const float4*)((const char*)y + (size_t)rb[s]*128 + cp*16));\
  }

#define WRITE(parX, src)                                                       \
  {                                                                            \
    char* wp = swb + (parX)*5120;                                              \
    _Pragma("unroll")                                                          \
    for (int s = 0; s < 10; ++s)                                               \
      *(uint2*)(wp + (s >> 1)*1024 + (s & 1)*512) = src[s];                    \
  }

#define AREAD(parX)                                                            \
  {                                                                            \
    const char* ap = arb + (parX)*5120;                                        \
    a0 = *(const bf16x8*)(ap);                                                 \
    a1 = *(const bf16x8*)(ap + 1024);                                          \
    a2 = *(const bf16x8*)(ap + 2048);                                          \
    a3 = *(const bf16x8*)(ap + 3072);                                          \
    a4 = *(const bf16x8*)(ap + 4096);                                          \
  }

// One r-pass: B fragment per j (canonical lane*16 read, 0 conflicts), 5 MFMA per
// B-read (one per vertex), A rotated in-register over the direction dim (DPP).
#define JLOOP(rr)                                                              \
  {                                                                            \
    const char* bp = bbase + (size_t)(rr)*16384;                               \
    __builtin_amdgcn_s_setprio(1);                                             \
    _Pragma("unroll")                                                          \
    for (int j = 0; j < 16; ++j) {                                             \
      const bf16x8 b = *(const bf16x8*)(bp + (size_t)j*1024);                  \
      acc0 = __builtin_amdgcn_mfma_f32_16x16x32_bf16(a0, b, acc0, 0, 0, 0);    \
      acc1 = __builtin_amdgcn_mfma_f32_16x16x32_bf16(a1, b, acc1, 0, 0, 0);    \
      acc2 = __builtin_amdgcn_mfma_f32_16x16x32_bf16(a2, b, acc2, 0, 0, 0);    \
      acc3 = __builtin_amdgcn_mfma_f32_16x16x32_bf16(a3, b, acc3, 0, 0, 0);    \
      acc4 = __builtin_amdgcn_mfma_f32_16x16x32_bf16(a4, b, acc4, 0, 0, 0);    \
      if (j < 15) { a0 = rot16(a0); a1 = rot16(a1); a2 = rot16(a2);            \
                    a3 = rot16(a3); a4 = rot16(a4); }                          \
    }                                                                          \
    __builtin_amdgcn_s_setprio(0);                                             \
  }

// NOTE: min-occupancy arg RELAXED to 1. With LDS_TOT=134.7KB the kernel is
// LDS-bound to 1 block/CU (2 waves/SIMD) regardless; the old ",2" imposed a
// 128-VGPR hard cap (R3/R5: VGPR_Count==128 + GBs of scratch). ",1" lifts the
// cap to >=256 so the ~150-190-reg live set allocates cleanly, same occupancy.
__global__ __launch_bounds__(512, 1) void conv_kernel(
    const float* __restrict__ y,
    const int*   __restrict__ em,     // exp_map int pairs (b,v), flat (u*48 + r*16+dd)
    const float* __restrict__ bias,
    const unsigned short* __restrict__ bpack,
    float* __restrict__ out)
{
  extern __shared__ __align__(16) char smem[];
  const int fq  = blockIdx.x & 3;     // which 16-wide f quarter
  const int bl  = blockIdx.x >> 2;    // 0..63
  const int tid = threadIdx.x;
  const int w   = tid >> 6;           // wave 0..7
  const int l   = tid & 63;

  // ---- stage this f-quarter's B fragments into LDS (once per block) ----
  {
    const uint4* src = (const uint4*)(bpack + (size_t)fq * BPACK_Q_USHORT);
    uint4* dst = (uint4*)smem;
    for (int idx = tid; idx < LDS_B16/16; idx += 512) dst[idx] = src[idx];
  }
  __syncthreads();   // the ONLY barrier — B-pack is read-only afterwards

  const char* bbase = smem + (size_t)l * 16;     // canonical fragment read
  char* const patch = smem + LDS_B16 + w*WPATCH; // PRIVATE: 2 slots x 5 verts + center
  const int d  = l & 15;              // A-operand: direction row (m)
  const int g4 = l >> 4;              // A/B operand: k-group selector
  const float biasv = bias[fq*16 + d];

  // staging lane roles: 8 lanes x 16B cover a 128B fp32 row
  const int rsl = l >> 3, cp = l & 7;
  char* const swb = patch + rsl*64 + cp*8;       // + par*5120 + v*1024 + (s&1)*512
  const char* const arb = patch + d*64 + g4*16;  // + par*5120 + v*1024
  char* const cwb = patch + 2*5120 + rsl*64 + cp*8;   // center write (lanes 0..39)
  const char* const crb = patch + 2*5120 + g4*16;     // center read (+v*64, bcast over d)

  const int wid = bl*8 + w;           // wave-task id within this f-quarter: 0..511

  int rowiX[10], rowiY[10];
  uint2 sv[10];

  // ---- prologue: stage group wid's r=0 into slot0; em(r1) -> rowiX ----
  EMLOAD(rowiY, wid, 0)
  YSTAGE(sv, rowiY)
  WRITE(0, sv)
  EMLOAD(rowiX, wid, 1)

  int par = 0;
  for (int g = wid; g < NGRP5; g += 512) {
    const int gn = g + 512;
    const int gp = (gn < NGRP5) ? gn : g;   // clamped prefetch (results unused on last iter)

    f32x4 acc0, acc1, acc2, acc3, acc4;
#pragma unroll
    for (int k = 0; k < 4; ++k) { acc0[k]=0.f; acc1[k]=0.f; acc2[k]=0.f; acc3[k]=0.f; acc4[k]=0.f; }

    bf16x8 a0, a1, a2, a3, a4;

    // ---- phase 0: compute r=0 from slot par; stage r=1 -> slot par^1 ----
    AREAD(par)
    YSTAGE(sv, rowiX)      // r=1 rows (em prefetched last phase 2 / prologue)
    // center rows for g -> LDS (lanes 0..39; 5 rows x 64B bf16), read after JLOOP(0)
    if (l < 40)
      *(uint2*)(cwb) = pack4(*(const float4*)((const char*)y + (size_t)(g*5 + rsl)*128 + cp*16));
    EMLOAD(rowiY, g, 2)    // em for r=2
    JLOOP(0)
    WRITE(par^1, sv)

    // ---- center term: A broadcast over d from LDS (transient frags, 5 MFMAs) ----
    {
      const bf16x8 bc = *(const bf16x8*)(bbase + 48*1024);
      acc0 = __builtin_amdgcn_mfma_f32_16x16x32_bf16(*(const bf16x8*)(crb),        bc, acc0, 0, 0, 0);
      acc1 = __builtin_amdgcn_mfma_f32_16x16x32_bf16(*(const bf16x8*)(crb + 64),   bc, acc1, 0, 0, 0);
      acc2 = __builtin_amdgcn_mfma_f32_16x16x32_bf16(*(const bf16x8*)(crb + 128),  bc, acc2, 0, 0, 0);
      acc3 = __builtin_amdgcn_mfma_f32_16x16x32_bf16(*(const bf16x8*)(crb + 192),  bc, acc3, 0, 0, 0);
      acc4 = __builtin_amdgcn_mfma_f32_16x16x32_bf16(*(const bf16x8*)(crb + 256),  bc, acc4, 0, 0, 0);
    }

    // ---- phase 1: compute r=1 from slot par^1; stage r=2 -> slot par ----
    AREAD(par^1)
    YSTAGE(sv, rowiY)      // r=2 rows
    EMLOAD(rowiY, gp, 0)   // em for next iter r=0 (consume-then-reload)
    JLOOP(1)
    WRITE(par, sv)

    // ---- phase 2: compute r=2 from slot par; stage next r=0 -> slot par^1 ----
    AREAD(par)
    YSTAGE(sv, rowiY)      // next iter r=0 rows
    EMLOAD(rowiX, gp, 1)   // em for next iter r=1
    JLOOP(2)
    WRITE(par^1, sv)

    // ---- epilogue: C/D 16x16 (m89): col = lane&15 = f, row = (lane>>4)*4+reg = dd.
    // max over dd = max over 4 regs then lane-groups (xor 16, 32); +bias, relu.
    {
      float m0 = fmaxf(fmaxf(acc0[0], acc0[1]), fmaxf(acc0[2], acc0[3]));
      float m1 = fmaxf(fmaxf(acc1[0], acc1[1]), fmaxf(acc1[2], acc1[3]));
      float m2 = fmaxf(fmaxf(acc2[0], acc2[1]), fmaxf(acc2[2], acc2[3]));
      float m3 = fmaxf(fmaxf(acc3[0], acc3[1]), fmaxf(acc3[2], acc3[3]));
      float m4 = fmaxf(fmaxf(acc4[0], acc4[1]), fmaxf(acc4[2], acc4[3]));
      m0 = fmaxf(m0, __shfl_xor(m0, 16)); m0 = fmaxf(m0, __shfl_xor(m0, 32));
      m1 = fmaxf(m1, __shfl_xor(m1, 16)); m1 = fmaxf(m1, __shfl_xor(m1, 32));
      m2 = fmaxf(m2, __shfl_xor(m2, 16)); m2 = fmaxf(m2, __shfl_xor(m2, 32));
      m3 = fmaxf(m3, __shfl_xor(m3, 16)); m3 = fmaxf(m3, __shfl_xor(m3, 32));
      m4 = fmaxf(m4, __shfl_xor(m4, 16)); m4 = fmaxf(m4, __shfl_xor(m4, 32));
      // verts g*5+0..3 via g4-select (all 64 lanes store distinct (vert, f))
      const float sel = (g4 == 0) ? m0 : (g4 == 1) ? m1 : (g4 == 2) ? m2 : m3;
      out[(size_t)(g*5 + g4)*64 + fq*16 + d] = fmaxf(sel + biasv, 0.f);
      // vert g*5+4: lanes 0..15
      if (l < 16)
        out[(size_t)(g*5 + 4)*64 + fq*16 + l] = fmaxf(m4 + biasv, 0.f);
    }

    par ^= 1;
  }
}

extern "C" void kernel_launch(void* const* d_in, const int* in_sizes, int n_in,
                              void* d_out, int out_size, void* d_ws, size_t ws_size,
                              hipStream_t stream) {
  const float* y     = (const float*)d_in[0];
  const int*   em    = (const int*)  d_in[1];
  const float* kern  = (const float*)d_in[2];
  const float* ckern = (const float*)d_in[3];
  const float* bias  = (const float*)d_in[4];
  float* out = (float*)d_out;
  unsigned short* bpack = (unsigned short*)d_ws;   // 200704 bytes used

  // opt in to >64KB dynamic LDS (host-side, graph-capture safe — verified many rounds)
  hipFuncSetAttribute(reinterpret_cast<const void*>(conv_kernel),
                      hipFuncAttributeMaxDynamicSharedMemorySize, LDS_TOT);

  prepack_kernel<<<(4*BPACK_Q_USHORT + 255)/256, 256, 0, stream>>>(kern, ckern, bpack);
  conv_kernel<<<256, 512, LDS_TOT, stream>>>(y, em, bias, bpack, out);
}